// Round 22
// baseline (363.708 us; speedup 1.0000x reference)
//
#include <hip/hip_runtime.h>
#include <hip/hip_bf16.h>
#include <cstdint>

typedef _Float16 f16x8 __attribute__((ext_vector_type(8)));
typedef _Float16 f16x2 __attribute__((ext_vector_type(2)));
typedef float  f32x4  __attribute__((ext_vector_type(4)));
typedef unsigned short u16x8 __attribute__((ext_vector_type(8)));

#define GLDS(gp, lp) __builtin_amdgcn_global_load_lds( \
    (const __attribute__((address_space(1))) void*)(gp), \
    (__attribute__((address_space(3))) void*)(lp), 16, 0, 0)

static constexpr int   MROWS = 16384;   // B*N = 16*1024
static constexpr int   N3    = 3072;    // 3*C
static constexpr int   NT    = 16;      // K-tiles of 64 (K = 1024, single-term fp16)
static constexpr float SCALE = 0.125f;  // 8/64

#if __has_builtin(__builtin_amdgcn_fdot2)
#define FDOT2(a, b, c) __builtin_amdgcn_fdot2((a), (b), (c), false)
#else
__device__ __forceinline__ float FDOT2(f16x2 a, f16x2 b, float c) {
  return c + (float)a[0] * (float)b[0] + (float)a[1] * (float)b[1];
}
#endif

__device__ __forceinline__ unsigned short f2h_u(float f) {
  union { _Float16 h; unsigned short u; } c; c.h = (_Float16)f; return c.u;
}
__device__ __forceinline__ float h2f(unsigned short u) {
  union { unsigned short u; _Float16 h; } c; c.u = u; return (float)c.h;
}
// swap the two 5-bit (h,w) fields within each batch's 1024 rows (involution)
__device__ __forceinline__ int permrow(int m) {
  return (m & ~1023) | ((m & 31) << 5) | ((m >> 5) & 31);
}

// ---- fp32 -> plain fp16 rows (x and W; single-term quantization) ----
__global__ __launch_bounds__(256) void split_h(const float* __restrict__ src,
                                               unsigned short* __restrict__ dst) {
  int idx = blockIdx.x * 256 + threadIdx.x;
  int m = idx >> 7, k8 = (idx & 127) << 3;
  const float* s = src + (size_t)m * 1024 + k8;
  float4 v0 = *(const float4*)s;
  float4 v1 = *(const float4*)(s + 4);
  float vals[8] = {v0.x, v0.y, v0.z, v0.w, v1.x, v1.y, v1.z, v1.w};
  u16x8 hi;
#pragma unroll
  for (int i = 0; i < 8; ++i) hi[i] = f2h_u(vals[i]);
  *(u16x8*)(dst + (size_t)m * 1024 + k8) = hi;
}

// ================= 256x256 8-wave fp16 GEMM, 1-barrier-per-K-tile =========
// (r18 proven version: 107us, MfmaUtil 43%. Schedule plateau confirmed —
// r5/r19/r20 overlap attempts all null or regressed. FROZEN.)
__global__ __launch_bounds__(512, 2) void gemm256(const unsigned short* __restrict__ A,
                                                  const unsigned short* __restrict__ Bm,
                                                  unsigned short* __restrict__ Cq) {
  __shared__ unsigned char smem[131072];
  const int tid = threadIdx.x;
  const int w = tid >> 6, l = tid & 63;
  const int wr = w >> 2, wc = w & 3;          // 2 x 4 wave grid

  // XCD-chunked, n-fast within chunk (768 = 8 XCDs x 8 m-panels x 12 n-panels)
  const int bid = blockIdx.x;
  const int xcd = bid & 7, ic = bid >> 3;
  const int m0 = (xcd * 8 + ic / 12) << 8;
  const int n0 = (ic % 12) << 8;

  // staging: wave w owns rows w*32..w*32+31 of each 16KB unit; pre-swizzled k src
  const int ske = ((l & 3) * 8) ^ ((l >= 32) ? 16 : 0);
  const unsigned short* gA0 = A  + (size_t)(m0 + w * 32 + (l >> 2)) * 1024 + ske;
  const unsigned short* gA1 = gA0 + 16 * 1024;
  const unsigned short* gB0 = Bm + (size_t)(n0 + w * 32 + (l >> 2)) * 1024 + ske;
  const unsigned short* gB1 = gB0 + 16 * 1024;
  int kT = 0;                                 // k-elem offset of K-tile being staged

  // swizzled ds_read lane offset (16B frag at row lr, k-group l>>4)
  const int lr = l & 15;
  const int laneoff = ((lr * 64) + ((l >> 4) * 16)) ^ ((lr & 8) << 2);

#define STAGE_A(pb, kk) do { \
    GLDS(gA0 + kT + (kk) * 32, smem + (pb) * 65536 + (4 * w + (kk)) * 1024); \
    GLDS(gA1 + kT + (kk) * 32, smem + (pb) * 65536 + (4 * w + 2 + (kk)) * 1024); } while (0)
#define STAGE_B(pb, kk) do { \
    GLDS(gB0 + kT + (kk) * 32, smem + (pb) * 65536 + 32768 + (4 * w + (kk)) * 1024); \
    GLDS(gB1 + kT + (kk) * 32, smem + (pb) * 65536 + 32768 + (4 * w + 2 + (kk)) * 1024); } while (0)
#define MFMA(af, bf, c) __builtin_amdgcn_mfma_f32_16x16x32_f16(af, bf, c, 0, 0, 0)

  f32x4 acc[8][4] = {};

  // ---- prologue: stage K-tile 0 into buf 0, drain, sync ----
  STAGE_A(0, 0); STAGE_B(0, 0); STAGE_A(0, 1); STAGE_B(0, 1);
  kT = 64;
  asm volatile("s_waitcnt vmcnt(0)" ::: "memory");
  __builtin_amdgcn_s_barrier();

  for (int t = 0; t < NT; ++t) {
    const int p = t & 1, q = p ^ 1;
    const unsigned char* rb = smem + p * 65536;

    // issue next-tile staging FIRST (8 gloads; lands during this tile's compute)
    if (t < NT - 1) { STAGE_A(q, 0); STAGE_B(q, 0); STAGE_A(q, 1); STAGE_B(q, 1); }

    // whole K-tile straight-line: compiler interleaves ds_read_b128 with MFMA
#pragma unroll
    for (int kk = 0; kk < 2; ++kk) {
      const unsigned char* rk = rb + kk * 1024;
      f16x8 a[8], b[4];
#pragma unroll
      for (int mi = 0; mi < 8; ++mi)
        a[mi] = *(const f16x8*)(rk + (wr * 8 + mi) * 2048 + laneoff);
#pragma unroll
      for (int ni = 0; ni < 4; ++ni)
        b[ni] = *(const f16x8*)(rk + 32768 + (wc * 4 + ni) * 2048 + laneoff);
#pragma unroll
      for (int mi = 0; mi < 8; ++mi)
#pragma unroll
        for (int ni = 0; ni < 4; ++ni)
          acc[mi][ni] = MFMA(a[mi], b[ni], acc[mi][ni]);
    }

    if (t < NT - 1) {
      asm volatile("s_waitcnt vmcnt(0)" ::: "memory");
      __builtin_amdgcn_s_barrier();
    }
    kT += 64;
  }

  // ---- epilogue: acc -> fp16 C ----
  const int rq = (l >> 4) * 4;
#pragma unroll
  for (int mi = 0; mi < 8; ++mi)
#pragma unroll
    for (int ni = 0; ni < 4; ++ni) {
      int row = m0 + wr * 128 + mi * 16 + rq;
      int col = n0 + wc * 64 + ni * 16 + lr;
      unsigned short* cp = Cq + (size_t)row * N3 + col;
#pragma unroll
      for (int r = 0; r < 4; ++r)
        cp[(size_t)r * N3] = f2h_u(acc[mi][ni][r]);
    }
#undef STAGE_A
#undef STAGE_B
#undef MFMA
}

// ---- per (seq, head): fused-LN + softmax(q*s @ k^T) @ v; fp16 in ----
// r21 structure + kh stride 72 -> 136 halves (68 dwords, 16B-aligned):
// logits k-reads drop from 4-way to 2-way (free) bank conflicts —
// c0 in {0,4,..,28}: (34*c0)%32 = {0,8,16,24}x2 vs old (36*c0)%32 = {0,16}x4.
// Layout-only change: arithmetic bit-identical to r21.
__global__ __launch_bounds__(256) void attn(const unsigned short* __restrict__ qkv,
                                            const float* __restrict__ gamma,
                                            const float* __restrict__ beta,
                                            float* __restrict__ out,
                                            unsigned short* __restrict__ a2,
                                            int mode) {
  __shared__ _Float16 qh[32][72];        // q_ln*SCALE fp16 (reads conflict-free)
  __shared__ _Float16 kh[32][136];       // k_ln fp16, stride 136 -> 2-way k-reads
  __shared__ unsigned short vh[32][72];  // RAW fp16 v bits (exact)
  __shared__ float pr[32][36];
  const int tid = threadIdx.x;
  const int s = blockIdx.x >> 4, hd = blockIdx.x & 15;
  const int p = tid >> 3, d0 = (tid & 7) * 8;
  const size_t base = (size_t)s * 32 * 3072 + hd * 64;

  // ---- load + fused LayerNorm ----
  {
    size_t r = base + (size_t)p * 3072 + d0;
    u16x8 qa = *(const u16x8*)(qkv + r);
    u16x8 ka = *(const u16x8*)(qkv + r + 1024);
    u16x8 va = *(const u16x8*)(qkv + r + 2048);
    float qf[8], kf[8];
    float q1 = 0.f, q2 = 0.f, k1 = 0.f, k2 = 0.f;
#pragma unroll
    for (int j = 0; j < 8; ++j) {
      qf[j] = h2f(qa[j]); kf[j] = h2f(ka[j]);
      q1 += qf[j]; q2 += qf[j] * qf[j];
      k1 += kf[j]; k2 += kf[j] * kf[j];
    }
#pragma unroll
    for (int m = 1; m <= 4; m <<= 1) {
      q1 += __shfl_xor(q1, m); q2 += __shfl_xor(q2, m);
      k1 += __shfl_xor(k1, m); k2 += __shfl_xor(k2, m);
    }
    float muq = q1 * 0.015625f, muk = k1 * 0.015625f;
    float rsq = rsqrtf(q2 * 0.015625f - muq * muq + 1e-5f);
    float rsk = rsqrtf(k2 * 0.015625f - muk * muk + 1e-5f);
    f32x4 g0 = *(const f32x4*)(gamma + d0);
    f32x4 g1 = *(const f32x4*)(gamma + d0 + 4);
    f32x4 b0 = *(const f32x4*)(beta + d0);
    f32x4 b1 = *(const f32x4*)(beta + d0 + 4);
    f16x8 qn16, kn16;
#pragma unroll
    for (int j = 0; j < 8; ++j) {
      float gg = (j < 4) ? g0[j] : g1[j - 4];
      float bb = (j < 4) ? b0[j] : b1[j - 4];
      qn16[j] = (_Float16)(((qf[j] - muq) * rsq * gg + bb) * SCALE);
      kn16[j] = (_Float16)((kf[j] - muk) * rsk * gg + bb);
    }
    *(f16x8*)&qh[p][d0] = qn16;
    *(f16x8*)&kh[p][d0] = kn16;
    *(u16x8*)&vh[p][d0] = va;            // raw bits, exact
  }
  __syncthreads();

  // ---- logits: thread (r=p, c0): pr[r][c0..c0+3] via fdot2 ----
  {
    const int c0 = (tid & 7) * 4;
    float a0 = 0.f, a1 = 0.f, a2f = 0.f, a3 = 0.f;
#pragma unroll
    for (int dc = 0; dc < 8; ++dc) {
      union { f16x8 v8; f16x2 p2[4]; } qa, k0, k1, k2, k3;
      qa.v8 = *(const f16x8*)&qh[p][dc * 8];
      k0.v8 = *(const f16x8*)&kh[c0 + 0][dc * 8];
      k1.v8 = *(const f16x8*)&kh[c0 + 1][dc * 8];
      k2.v8 = *(const f16x8*)&kh[c0 + 2][dc * 8];
      k3.v8 = *(const f16x8*)&kh[c0 + 3][dc * 8];
#pragma unroll
      for (int j = 0; j < 4; ++j) {
        a0  = FDOT2(qa.p2[j], k0.p2[j], a0);
        a1  = FDOT2(qa.p2[j], k1.p2[j], a1);
        a2f = FDOT2(qa.p2[j], k2.p2[j], a2f);
        a3  = FDOT2(qa.p2[j], k3.p2[j], a3);
      }
    }
    f32x4 res; res[0] = a0; res[1] = a1; res[2] = a2f; res[3] = a3;
    *(f32x4*)&pr[p][c0] = res;
  }
  __syncthreads();

  // ---- softmax rows (8 lanes per row) ----
  {
    const int c0 = (tid & 7) * 4;
    f32x4 e = *(const f32x4*)&pr[p][c0];
    float mx = fmaxf(fmaxf(e[0], e[1]), fmaxf(e[2], e[3]));
#pragma unroll
    for (int m = 1; m <= 4; m <<= 1) mx = fmaxf(mx, __shfl_xor(mx, m));
    e[0] = __expf(e[0] - mx); e[1] = __expf(e[1] - mx);
    e[2] = __expf(e[2] - mx); e[3] = __expf(e[3] - mx);
    float sum = e[0] + e[1] + e[2] + e[3];
#pragma unroll
    for (int m = 1; m <= 4; m <<= 1) sum += __shfl_xor(sum, m);
    float inv = 1.f / sum;
    e[0] *= inv; e[1] *= inv; e[2] *= inv; e[3] *= inv;
    *(f32x4*)&pr[p][c0] = e;
  }
  __syncthreads();

  // ---- PV + permuted store (pr row preloaded; v read as fp16, cvt in reg) ----
  {
    f32x4 prr[8];
#pragma unroll
    for (int jq = 0; jq < 8; ++jq) prr[jq] = *(const f32x4*)&pr[p][jq * 4];
    f32x4 o0 = {0.f, 0.f, 0.f, 0.f}, o1 = {0.f, 0.f, 0.f, 0.f};
#pragma unroll
    for (int j = 0; j < 32; ++j) {
      float pj = prr[j >> 2][j & 3];   // fully unrolled -> compile-time indices
      u16x8 vv = *(const u16x8*)&vh[j][d0];
#pragma unroll
      for (int d = 0; d < 4; ++d) {
        o0[d] += pj * h2f(vv[d]);
        o1[d] += pj * h2f(vv[4 + d]);
      }
    }
    int pm = permrow(s * 32 + p);
    if (mode == 0) {
      u16x8 hv;
#pragma unroll
      for (int j = 0; j < 4; ++j) {
        hv[j]     = f2h_u(o0[j]);
        hv[4 + j] = f2h_u(o1[j]);
      }
      *(u16x8*)(a2 + (size_t)pm * 1024 + hd * 64 + d0) = hv;
    } else {
      float* op = out + (size_t)pm * 1024 + hd * 64 + d0;
      *(f32x4*)op       = o0;
      *(f32x4*)(op + 4) = o1;
    }
  }
}

extern "C" void kernel_launch(void* const* d_in, const int* in_sizes, int n_in,
                              void* d_out, int out_size, void* d_ws, size_t ws_size,
                              hipStream_t stream) {
  const float* x    = (const float*)d_in[0];
  const float* Wrow = (const float*)d_in[1];
  const float* Wcol = (const float*)d_in[2];
  const float* grow = (const float*)d_in[3];
  const float* brow = (const float*)d_in[4];
  const float* gcol = (const float*)d_in[5];
  const float* bcol = (const float*)d_in[6];
  float* out = (float*)d_out;

  char* ws = (char*)d_ws;
  const size_t szA2 = (size_t)MROWS * 1024 * 2;   // 33554432
  const size_t szB2 = (size_t)N3 * 1024 * 2;      // 6291456
  unsigned short* A2   = (unsigned short*)ws;
  unsigned short* B2   = (unsigned short*)(ws + szA2);
  unsigned short* qkvh = (unsigned short*)(ws + szA2 + szB2);  // 16384*3072*2

  // pass 0 (rows)
  split_h<<<8192, 256, 0, stream>>>(x, A2);
  split_h<<<1536, 256, 0, stream>>>(Wrow, B2);
  gemm256<<<768, 512, 0, stream>>>(A2, B2, qkvh);
  attn<<<8192, 256, 0, stream>>>(qkvh, grow, brow, out, A2, 0);  // writes A2 (permuted)
  // pass 1 (cols)
  split_h<<<1536, 256, 0, stream>>>(Wcol, B2);
  gemm256<<<768, 512, 0, stream>>>(A2, B2, qkvh);
  attn<<<8192, 256, 0, stream>>>(qkvh, gcol, bcol, out, A2, 1);  // writes out
}

// Round 23
// 354.962 us; speedup vs baseline: 1.0246x; 1.0246x over previous
//
#include <hip/hip_runtime.h>
#include <hip/hip_bf16.h>
#include <cstdint>

typedef _Float16 f16x8 __attribute__((ext_vector_type(8)));
typedef _Float16 f16x2 __attribute__((ext_vector_type(2)));
typedef float  f32x4  __attribute__((ext_vector_type(4)));
typedef unsigned short u16x8 __attribute__((ext_vector_type(8)));

#define GLDS(gp, lp) __builtin_amdgcn_global_load_lds( \
    (const __attribute__((address_space(1))) void*)(gp), \
    (__attribute__((address_space(3))) void*)(lp), 16, 0, 0)

static constexpr int   MROWS = 16384;   // B*N = 16*1024
static constexpr int   N3    = 3072;    // 3*C
static constexpr int   NT    = 16;      // K-tiles of 64 (K = 1024, single-term fp16)
static constexpr float SCALE = 0.125f;  // 8/64

#if __has_builtin(__builtin_amdgcn_fdot2)
#define FDOT2(a, b, c) __builtin_amdgcn_fdot2((a), (b), (c), false)
#else
__device__ __forceinline__ float FDOT2(f16x2 a, f16x2 b, float c) {
  return c + (float)a[0] * (float)b[0] + (float)a[1] * (float)b[1];
}
#endif

__device__ __forceinline__ unsigned short f2h_u(float f) {
  union { _Float16 h; unsigned short u; } c; c.h = (_Float16)f; return c.u;
}
__device__ __forceinline__ float h2f(unsigned short u) {
  union { unsigned short u; _Float16 h; } c; c.u = u; return (float)c.h;
}
// swap the two 5-bit (h,w) fields within each batch's 1024 rows (involution)
__device__ __forceinline__ int permrow(int m) {
  return (m & ~1023) | ((m & 31) << 5) | ((m >> 5) & 31);
}

// ---- fp32 -> plain fp16 rows (x and W; single-term quantization) ----
__global__ __launch_bounds__(256) void split_h(const float* __restrict__ src,
                                               unsigned short* __restrict__ dst) {
  int idx = blockIdx.x * 256 + threadIdx.x;
  int m = idx >> 7, k8 = (idx & 127) << 3;
  const float* s = src + (size_t)m * 1024 + k8;
  float4 v0 = *(const float4*)s;
  float4 v1 = *(const float4*)(s + 4);
  float vals[8] = {v0.x, v0.y, v0.z, v0.w, v1.x, v1.y, v1.z, v1.w};
  u16x8 hi;
#pragma unroll
  for (int i = 0; i < 8; ++i) hi[i] = f2h_u(vals[i]);
  *(u16x8*)(dst + (size_t)m * 1024 + k8) = hi;
}

// ================= 256x256 8-wave fp16 GEMM, 1-barrier-per-K-tile =========
// (r18 banked version: 107us/dispatch, MfmaUtil 43%. Structure plateau:
// wall = MFMA(2480cy) + LDS(2260cy) + barrier, serialized; r5/r6/r7/r19/r20
// overlap attempts all null or regressed. FROZEN.)
__global__ __launch_bounds__(512, 2) void gemm256(const unsigned short* __restrict__ A,
                                                  const unsigned short* __restrict__ Bm,
                                                  unsigned short* __restrict__ Cq) {
  __shared__ unsigned char smem[131072];
  const int tid = threadIdx.x;
  const int w = tid >> 6, l = tid & 63;
  const int wr = w >> 2, wc = w & 3;          // 2 x 4 wave grid

  // XCD-chunked, n-fast within chunk (768 = 8 XCDs x 8 m-panels x 12 n-panels)
  const int bid = blockIdx.x;
  const int xcd = bid & 7, ic = bid >> 3;
  const int m0 = (xcd * 8 + ic / 12) << 8;
  const int n0 = (ic % 12) << 8;

  // staging: wave w owns rows w*32..w*32+31 of each 16KB unit; pre-swizzled k src
  const int ske = ((l & 3) * 8) ^ ((l >= 32) ? 16 : 0);
  const unsigned short* gA0 = A  + (size_t)(m0 + w * 32 + (l >> 2)) * 1024 + ske;
  const unsigned short* gA1 = gA0 + 16 * 1024;
  const unsigned short* gB0 = Bm + (size_t)(n0 + w * 32 + (l >> 2)) * 1024 + ske;
  const unsigned short* gB1 = gB0 + 16 * 1024;
  int kT = 0;                                 // k-elem offset of K-tile being staged

  // swizzled ds_read lane offset (16B frag at row lr, k-group l>>4)
  const int lr = l & 15;
  const int laneoff = ((lr * 64) + ((l >> 4) * 16)) ^ ((lr & 8) << 2);

#define STAGE_A(pb, kk) do { \
    GLDS(gA0 + kT + (kk) * 32, smem + (pb) * 65536 + (4 * w + (kk)) * 1024); \
    GLDS(gA1 + kT + (kk) * 32, smem + (pb) * 65536 + (4 * w + 2 + (kk)) * 1024); } while (0)
#define STAGE_B(pb, kk) do { \
    GLDS(gB0 + kT + (kk) * 32, smem + (pb) * 65536 + 32768 + (4 * w + (kk)) * 1024); \
    GLDS(gB1 + kT + (kk) * 32, smem + (pb) * 65536 + 32768 + (4 * w + 2 + (kk)) * 1024); } while (0)
#define MFMA(af, bf, c) __builtin_amdgcn_mfma_f32_16x16x32_f16(af, bf, c, 0, 0, 0)

  f32x4 acc[8][4] = {};

  // ---- prologue: stage K-tile 0 into buf 0, drain, sync ----
  STAGE_A(0, 0); STAGE_B(0, 0); STAGE_A(0, 1); STAGE_B(0, 1);
  kT = 64;
  asm volatile("s_waitcnt vmcnt(0)" ::: "memory");
  __builtin_amdgcn_s_barrier();

  for (int t = 0; t < NT; ++t) {
    const int p = t & 1, q = p ^ 1;
    const unsigned char* rb = smem + p * 65536;

    // issue next-tile staging FIRST (8 gloads; lands during this tile's compute)
    if (t < NT - 1) { STAGE_A(q, 0); STAGE_B(q, 0); STAGE_A(q, 1); STAGE_B(q, 1); }

    // whole K-tile straight-line: compiler interleaves ds_read_b128 with MFMA
#pragma unroll
    for (int kk = 0; kk < 2; ++kk) {
      const unsigned char* rk = rb + kk * 1024;
      f16x8 a[8], b[4];
#pragma unroll
      for (int mi = 0; mi < 8; ++mi)
        a[mi] = *(const f16x8*)(rk + (wr * 8 + mi) * 2048 + laneoff);
#pragma unroll
      for (int ni = 0; ni < 4; ++ni)
        b[ni] = *(const f16x8*)(rk + 32768 + (wc * 4 + ni) * 2048 + laneoff);
#pragma unroll
      for (int mi = 0; mi < 8; ++mi)
#pragma unroll
        for (int ni = 0; ni < 4; ++ni)
          acc[mi][ni] = MFMA(a[mi], b[ni], acc[mi][ni]);
    }

    if (t < NT - 1) {
      asm volatile("s_waitcnt vmcnt(0)" ::: "memory");
      __builtin_amdgcn_s_barrier();
    }
    kT += 64;
  }

  // ---- epilogue: acc -> fp16 C ----
  const int rq = (l >> 4) * 4;
#pragma unroll
  for (int mi = 0; mi < 8; ++mi)
#pragma unroll
    for (int ni = 0; ni < 4; ++ni) {
      int row = m0 + wr * 128 + mi * 16 + rq;
      int col = n0 + wc * 64 + ni * 16 + lr;
      unsigned short* cp = Cq + (size_t)row * N3 + col;
#pragma unroll
      for (int r = 0; r < 4; ++r)
        cp[(size_t)r * N3] = f2h_u(acc[mi][ni][r]);
    }
#undef STAGE_A
#undef STAGE_B
#undef MFMA
}

// ---- per (seq, head): fused-LN + softmax(q*s @ k^T) @ v; fp16 in ----
// (r18 banked version. attn plateau: three LDS micro-opts (r21 v-fp16,
// r22 kh-stride, plus pr-preload) all within noise -> latency/barrier-bound,
// not LDS-throughput-bound. FROZEN.)
__global__ __launch_bounds__(256) void attn(const unsigned short* __restrict__ qkv,
                                            const float* __restrict__ gamma,
                                            const float* __restrict__ beta,
                                            float* __restrict__ out,
                                            unsigned short* __restrict__ a2,
                                            int mode) {
  __shared__ _Float16 qh[32][72];  // q_ln*SCALE fp16, 64+8 pad
  __shared__ _Float16 kh[32][72];  // k_ln fp16, 64+8 pad
  __shared__ float v[32][68];      // fp32
  __shared__ float pr[32][36];
  const int tid = threadIdx.x;
  const int s = blockIdx.x >> 4, hd = blockIdx.x & 15;
  const int p = tid >> 3, d0 = (tid & 7) * 8;
  const size_t base = (size_t)s * 32 * 3072 + hd * 64;

  // ---- load + fused LayerNorm ----
  {
    size_t r = base + (size_t)p * 3072 + d0;
    u16x8 qa = *(const u16x8*)(qkv + r);
    u16x8 ka = *(const u16x8*)(qkv + r + 1024);
    u16x8 va = *(const u16x8*)(qkv + r + 2048);
    float qf[8], kf[8];
    float q1 = 0.f, q2 = 0.f, k1 = 0.f, k2 = 0.f;
#pragma unroll
    for (int j = 0; j < 8; ++j) {
      qf[j] = h2f(qa[j]); kf[j] = h2f(ka[j]);
      q1 += qf[j]; q2 += qf[j] * qf[j];
      k1 += kf[j]; k2 += kf[j] * kf[j];
    }
#pragma unroll
    for (int m = 1; m <= 4; m <<= 1) {
      q1 += __shfl_xor(q1, m); q2 += __shfl_xor(q2, m);
      k1 += __shfl_xor(k1, m); k2 += __shfl_xor(k2, m);
    }
    float muq = q1 * 0.015625f, muk = k1 * 0.015625f;
    float rsq = rsqrtf(q2 * 0.015625f - muq * muq + 1e-5f);
    float rsk = rsqrtf(k2 * 0.015625f - muk * muk + 1e-5f);
    f32x4 g0 = *(const f32x4*)(gamma + d0);
    f32x4 g1 = *(const f32x4*)(gamma + d0 + 4);
    f32x4 b0 = *(const f32x4*)(beta + d0);
    f32x4 b1 = *(const f32x4*)(beta + d0 + 4);
    f16x8 qn16, kn16;
    f32x4 vv0, vv1;
#pragma unroll
    for (int j = 0; j < 8; ++j) {
      float gg = (j < 4) ? g0[j] : g1[j - 4];
      float bb = (j < 4) ? b0[j] : b1[j - 4];
      qn16[j] = (_Float16)(((qf[j] - muq) * rsq * gg + bb) * SCALE);
      kn16[j] = (_Float16)((kf[j] - muk) * rsk * gg + bb);
    }
#pragma unroll
    for (int j = 0; j < 4; ++j) { vv0[j] = h2f(va[j]); vv1[j] = h2f(va[4 + j]); }
    *(f16x8*)&qh[p][d0] = qn16;
    *(f16x8*)&kh[p][d0] = kn16;
    *(f32x4*)&v[p][d0]     = vv0;
    *(f32x4*)&v[p][d0 + 4] = vv1;
  }
  __syncthreads();

  // ---- logits: thread (r=p, c0): pr[r][c0..c0+3] via fdot2 ----
  {
    const int c0 = (tid & 7) * 4;
    float a0 = 0.f, a1 = 0.f, a2f = 0.f, a3 = 0.f;
#pragma unroll
    for (int dc = 0; dc < 8; ++dc) {
      union { f16x8 v8; f16x2 p2[4]; } qa, k0, k1, k2, k3;
      qa.v8 = *(const f16x8*)&qh[p][dc * 8];
      k0.v8 = *(const f16x8*)&kh[c0 + 0][dc * 8];
      k1.v8 = *(const f16x8*)&kh[c0 + 1][dc * 8];
      k2.v8 = *(const f16x8*)&kh[c0 + 2][dc * 8];
      k3.v8 = *(const f16x8*)&kh[c0 + 3][dc * 8];
#pragma unroll
      for (int j = 0; j < 4; ++j) {
        a0  = FDOT2(qa.p2[j], k0.p2[j], a0);
        a1  = FDOT2(qa.p2[j], k1.p2[j], a1);
        a2f = FDOT2(qa.p2[j], k2.p2[j], a2f);
        a3  = FDOT2(qa.p2[j], k3.p2[j], a3);
      }
    }
    f32x4 res; res[0] = a0; res[1] = a1; res[2] = a2f; res[3] = a3;
    *(f32x4*)&pr[p][c0] = res;
  }
  __syncthreads();

  // ---- softmax rows (8 lanes per row) ----
  {
    const int c0 = (tid & 7) * 4;
    f32x4 e = *(const f32x4*)&pr[p][c0];
    float mx = fmaxf(fmaxf(e[0], e[1]), fmaxf(e[2], e[3]));
#pragma unroll
    for (int m = 1; m <= 4; m <<= 1) mx = fmaxf(mx, __shfl_xor(mx, m));
    e[0] = __expf(e[0] - mx); e[1] = __expf(e[1] - mx);
    e[2] = __expf(e[2] - mx); e[3] = __expf(e[3] - mx);
    float sum = e[0] + e[1] + e[2] + e[3];
#pragma unroll
    for (int m = 1; m <= 4; m <<= 1) sum += __shfl_xor(sum, m);
    float inv = 1.f / sum;
    e[0] *= inv; e[1] *= inv; e[2] *= inv; e[3] *= inv;
    *(f32x4*)&pr[p][c0] = e;
  }
  __syncthreads();

  // ---- PV + permuted store (pr row preloaded to registers) ----
  {
    f32x4 prr[8];
#pragma unroll
    for (int jq = 0; jq < 8; ++jq) prr[jq] = *(const f32x4*)&pr[p][jq * 4];
    f32x4 o0 = {0.f, 0.f, 0.f, 0.f}, o1 = {0.f, 0.f, 0.f, 0.f};
#pragma unroll
    for (int j = 0; j < 32; ++j) {
      float pj = prr[j >> 2][j & 3];   // fully unrolled -> compile-time indices
      f32x4 v0 = *(const f32x4*)&v[j][d0];
      f32x4 v1 = *(const f32x4*)&v[j][d0 + 4];
      o0 += pj * v0;
      o1 += pj * v1;
    }
    int pm = permrow(s * 32 + p);
    if (mode == 0) {
      u16x8 hv;
#pragma unroll
      for (int j = 0; j < 4; ++j) {
        hv[j]     = f2h_u(o0[j]);
        hv[4 + j] = f2h_u(o1[j]);
      }
      *(u16x8*)(a2 + (size_t)pm * 1024 + hd * 64 + d0) = hv;
    } else {
      float* op = out + (size_t)pm * 1024 + hd * 64 + d0;
      *(f32x4*)op       = o0;
      *(f32x4*)(op + 4) = o1;
    }
  }
}

extern "C" void kernel_launch(void* const* d_in, const int* in_sizes, int n_in,
                              void* d_out, int out_size, void* d_ws, size_t ws_size,
                              hipStream_t stream) {
  const float* x    = (const float*)d_in[0];
  const float* Wrow = (const float*)d_in[1];
  const float* Wcol = (const float*)d_in[2];
  const float* grow = (const float*)d_in[3];
  const float* brow = (const float*)d_in[4];
  const float* gcol = (const float*)d_in[5];
  const float* bcol = (const float*)d_in[6];
  float* out = (float*)d_out;

  char* ws = (char*)d_ws;
  const size_t szA2 = (size_t)MROWS * 1024 * 2;   // 33554432
  const size_t szB2 = (size_t)N3 * 1024 * 2;      // 6291456
  unsigned short* A2   = (unsigned short*)ws;
  unsigned short* B2   = (unsigned short*)(ws + szA2);
  unsigned short* qkvh = (unsigned short*)(ws + szA2 + szB2);  // 16384*3072*2

  // pass 0 (rows)
  split_h<<<8192, 256, 0, stream>>>(x, A2);
  split_h<<<1536, 256, 0, stream>>>(Wrow, B2);
  gemm256<<<768, 512, 0, stream>>>(A2, B2, qkvh);
  attn<<<8192, 256, 0, stream>>>(qkvh, grow, brow, out, A2, 0);  // writes A2 (permuted)
  // pass 1 (cols)
  split_h<<<1536, 256, 0, stream>>>(Wcol, B2);
  gemm256<<<768, 512, 0, stream>>>(A2, B2, qkvh);
  attn<<<8192, 256, 0, stream>>>(qkvh, gcol, bcol, out, A2, 1);  // writes out
}